// Round 3
// baseline (2200.246 us; speedup 1.0000x reference)
//
#include <hip/hip_runtime.h>
#include <cstdint>
#include <cstddef>

#define BB 256
#define TT 2048
#define VV 128
#define HH 64

__device__ __forceinline__ float frcp(float x){ return __builtin_amdgcn_rcpf(x); }
__device__ __forceinline__ float sigm(float x){ return frcp(1.f + __expf(-x)); }
__device__ __forceinline__ float tanh_f(float x){ return 1.f - 2.f*frcp(1.f + __expf(2.f*x)); }

// barrier with LDS visibility but NO vmcnt drain (keeps prefetch async)
__device__ __forceinline__ void bar_lds(){
  asm volatile("s_waitcnt lgkmcnt(0)" ::: "memory");
  __builtin_amdgcn_s_barrier();
  __builtin_amdgcn_sched_barrier(0);
}

__device__ __forceinline__ void gload16(const float* g, float* l){
  __builtin_amdgcn_global_load_lds(
      (const __attribute__((address_space(1))) void*)g,
      (__attribute__((address_space(3))) void*)l, 16, 0, 0);
}

// ring slot for step t: [0..127] = x_t, [128..191] = h_{t-1}
__global__ __launch_bounds__(512, 2) void lstm_k(
  const float* __restrict__ x,
  const float* __restrict__ W_f,  const float* __restrict__ b_f,
  const float* __restrict__ W_if, const float* __restrict__ b_if,
  const float* __restrict__ W_ic, const float* __restrict__ b_ic,
  const float* __restrict__ W_o,  const float* __restrict__ b_o,
  const float* __restrict__ W_out,const float* __restrict__ b_out,
  float* __restrict__ out)
{
  __shared__ __align__(16) float ring[4][VV+HH];

  const int tid  = threadIdx.x;
  const int wv   = tid >> 6;          // 8 waves
  const int l    = tid & 63;
  const int kseg = l & 7;             // k-octant: k in [24*kseg, 24*kseg+24)
  const int col  = wv*8 + (l >> 3);   // h column 0..63 (one per thread)
  const int row  = blockIdx.x;

  // per-thread gate weights: all 4 gates, 24 k's, 1 col  -> 96 VGPRs
  const int kbase = kseg*24;
  float w_f[24], w_i[24], w_c[24], w_o4[24];
  #pragma unroll
  for (int m=0;m<24;++m){
    const size_t k = (size_t)(kbase+m)*HH + col;
    w_f[m]  = W_f[k];
    w_i[m]  = W_if[k];
    w_c[m]  = W_ic[k];
    w_o4[m] = W_o[k];
  }
  const float bf = b_f[col], bi = b_if[col], bc = b_ic[col], bo = b_o[col];

  // logit slice: 4 threads per column j, 16 k's each
  const int j  = tid >> 2;            // 0..127
  const int kh = (tid & 3) * 16;
  float wo[16];
  #pragma unroll
  for (int m=0;m<16;++m) wo[m] = W_out[(size_t)(kh+m)*VV + j];
  const float bj = b_out[j];

  float c = 0.f;                      // redundant copy in all 8 kseg lanes of this col

  const float* xrow = x  + (size_t)row*TT*VV;
  float*       orow = out+ (size_t)row*TT*VV;

  // prologue: h_{-1} = 0; prefetch x_0, x_1
  if (tid < HH) ring[0][VV+tid] = 0.f;
  if (wv==0 && l<32) {
    gload16(xrow +      l*4, &ring[0][0]);
    gload16(xrow + VV + l*4, &ring[1][0]);
  }
  if (wv==0) asm volatile("s_waitcnt vmcnt(1)" ::: "memory"); // x0 landed
  bar_lds();

  #pragma unroll 1
  for (int t=0; t<TT; ++t) {
    // ---- gates: 6x ds_read_b128 of the k-slice, 96 FMAs (4 chains of 24)
    const float4* sp = (const float4*)(&ring[t&3][kbase]);
    float a0=0.f,a1=0.f,a2=0.f,a3=0.f;
    #pragma unroll
    for (int m4=0;m4<6;++m4){
      const float4 v = sp[m4];
      a0=fmaf(v.x,w_f [4*m4+0],a0); a0=fmaf(v.y,w_f [4*m4+1],a0);
      a0=fmaf(v.z,w_f [4*m4+2],a0); a0=fmaf(v.w,w_f [4*m4+3],a0);
      a1=fmaf(v.x,w_i [4*m4+0],a1); a1=fmaf(v.y,w_i [4*m4+1],a1);
      a1=fmaf(v.z,w_i [4*m4+2],a1); a1=fmaf(v.w,w_i [4*m4+3],a1);
      a2=fmaf(v.x,w_c [4*m4+0],a2); a2=fmaf(v.y,w_c [4*m4+1],a2);
      a2=fmaf(v.z,w_c [4*m4+2],a2); a2=fmaf(v.w,w_c [4*m4+3],a2);
      a3=fmaf(v.x,w_o4[4*m4+0],a3); a3=fmaf(v.y,w_o4[4*m4+1],a3);
      a3=fmaf(v.z,w_o4[4*m4+2],a3); a3=fmaf(v.w,w_o4[4*m4+3],a3);
    }
    // combine across kseg lanes (bits 0-2): xor1,2 = quad DPP (VALU), xor4 = swizzle
    a0 += __shfl_xor(a0,1); a0 += __shfl_xor(a0,2); a0 += __shfl_xor(a0,4);
    a1 += __shfl_xor(a1,1); a1 += __shfl_xor(a1,2); a1 += __shfl_xor(a1,4);
    a2 += __shfl_xor(a2,1); a2 += __shfl_xor(a2,2); a2 += __shfl_xor(a2,4);
    a3 += __shfl_xor(a3,1); a3 += __shfl_xor(a3,2); a3 += __shfl_xor(a3,4);

    const float f  = sigm(a0 + bf);
    const float af = sigm(a1 + bi);
    const float ad = tanh_f(a2 + bc);
    const float o  = sigm(a3 + bo);
    c = c*f + ad*af;
    const float hv = tanh_f(c) * o;
    if ((l&7)==0) ring[(t+1)&3][VV+col] = hv;   // one writer lane per col

    // issue prefetch for x_{t+2}
    if (wv==0 && t+2<TT && l<32)
      gload16(xrow + (size_t)(t+2)*VV + l*4, &ring[(t+2)&3][0]);

    // wave0 counted wait: x_{t+1} must be in LDS before the barrier releases
    if (wv==0) {
      if (t==0 || t+2>=TT) {
        if (t+1<TT) asm volatile("s_waitcnt vmcnt(1)" ::: "memory");
      } else {
        // outstanding: {gload(t+1), store(t-1), gload(t+2)} -> keep newest 2
        asm volatile("s_waitcnt vmcnt(2)" ::: "memory");
      }
    }
    bar_lds();   // single barrier per step: publishes h_t (+ x arrivals)

    // ---- logits: 4x ds_read_b128 of h_t, 16 FMA, quad combine; raw logits out
    const float4* hp = (const float4*)(&ring[(t+1)&3][VV+kh]);
    float p0=0.f, p1=0.f;
    #pragma unroll
    for (int m4=0;m4<4;++m4){
      const float4 v = hp[m4];
      p0=fmaf(v.x,wo[4*m4+0],p0); p0=fmaf(v.y,wo[4*m4+1],p0);
      p1=fmaf(v.z,wo[4*m4+2],p1); p1=fmaf(v.w,wo[4*m4+3],p1);
    }
    float p = p0+p1;
    p += __shfl_xor(p,1);
    p += __shfl_xor(p,2);
    if ((l&3)==0) orow[(size_t)t*VV + j] = p + bj;
  }
}

// epilogue: in-place softmax over [B*T, 128]; one wave per row
__global__ __launch_bounds__(256) void softmax_k(float* __restrict__ out)
{
  const int r = blockIdx.x*4 + (threadIdx.x>>6);
  const int l = threadIdx.x & 63;
  float2* p = (float2*)(out + (size_t)r*VV);
  float2 v = p[l];
  float m = fmaxf(v.x, v.y);
  #pragma unroll
  for (int d=1; d<64; d<<=1) m = fmaxf(m, __shfl_xor(m, d));
  float e0 = __expf(v.x - m), e1 = __expf(v.y - m);
  float s = e0 + e1;
  #pragma unroll
  for (int d=1; d<64; d<<=1) s += __shfl_xor(s, d);
  float rs = frcp(s);
  p[l] = make_float2(e0*rs, e1*rs);
}

extern "C" void kernel_launch(void* const* d_in, const int* in_sizes, int n_in,
                              void* d_out, int out_size, void* d_ws, size_t ws_size,
                              hipStream_t stream) {
  const float* x     = (const float*)d_in[0];
  const float* W_f   = (const float*)d_in[1];
  const float* b_f   = (const float*)d_in[2];
  const float* W_if  = (const float*)d_in[3];
  const float* b_if  = (const float*)d_in[4];
  const float* W_ic  = (const float*)d_in[5];
  const float* b_ic  = (const float*)d_in[6];
  const float* W_o   = (const float*)d_in[7];
  const float* b_o   = (const float*)d_in[8];
  const float* W_out = (const float*)d_in[9];
  const float* b_out = (const float*)d_in[10];
  float* out = (float*)d_out;

  hipLaunchKernelGGL(lstm_k, dim3(BB), dim3(512), 0, stream,
                     x, W_f, b_f, W_if, b_if, W_ic, b_ic, W_o, b_o,
                     W_out, b_out, out);
  hipLaunchKernelGGL(softmax_k, dim3(BB*TT/4), dim3(256), 0, stream, out);
}

// Round 4
// 1301.976 us; speedup vs baseline: 1.6899x; 1.6899x over previous
//
#include <hip/hip_runtime.h>
#include <cstdint>
#include <cstddef>

#define TT 2048
#define VV 128
#define HH 64
#define NB 128   // 16-step blocks

typedef __attribute__((ext_vector_type(8))) short short8;
typedef __attribute__((ext_vector_type(4))) float f32x4;

__device__ __forceinline__ float frcp(float x){ return __builtin_amdgcn_rcpf(x); }
__device__ __forceinline__ float sigm(float x){ return frcp(1.f + __expf(-x)); }
__device__ __forceinline__ float tanh_f(float x){ return 1.f - 2.f*frcp(1.f + __expf(2.f*x)); }

__device__ __forceinline__ void bar_lds(){
  asm volatile("s_waitcnt lgkmcnt(0)" ::: "memory");
  __builtin_amdgcn_s_barrier();
  __builtin_amdgcn_sched_barrier(0);
}

__device__ __forceinline__ void gload16(const float* g, float* l){
  __builtin_amdgcn_global_load_lds(
      (const __attribute__((address_space(1))) void*)g,
      (__attribute__((address_space(3))) void*)l, 16, 0, 0);
}

__device__ __forceinline__ unsigned short bf16hi(float x){
  unsigned u = __float_as_uint(x);
  return (unsigned short)((u + 0x7fffu + ((u>>16)&1u)) >> 16);
}

__device__ __forceinline__ void splitpack(const float* v8, short8& hi, short8& lo){
  #pragma unroll
  for (int j=0;j<8;++j){
    unsigned short h = bf16hi(v8[j]);
    float fh = __uint_as_float(((unsigned)h)<<16);
    unsigned short lw = bf16hi(v8[j] - fh);
    hi[j] = (short)h; lo[j] = (short)lw;
  }
}

// quad butterfly sum via DPP quad_perm (VALU pipe, no LDS)
__device__ __forceinline__ float qsum(float v){
  int t1 = __builtin_amdgcn_update_dpp(0, __float_as_int(v), 0xB1, 0xF, 0xF, true);
  v += __int_as_float(t1);
  int t2 = __builtin_amdgcn_update_dpp(0, __float_as_int(v), 0x4E, 0xF, 0xF, true);
  v += __int_as_float(t2);
  return v;
}

// XA: [buf2][kk4][q4][s16][8] bf16 ; HA: [buf2][kk2][q4][s16][8]
#define XA_IDX(buf,kk,q,s) ((buf)*2048 + (((kk)*4+(q))*16+(s))*8)
#define HA_IDX(buf,kk,q,s) ((buf)*1024 + (((kk)*4+(q))*16+(s))*8)

__global__ __launch_bounds__(512, 1) void lstm_k(
  const float* __restrict__ x,
  const float* __restrict__ W_f,  const float* __restrict__ b_f,
  const float* __restrict__ W_if, const float* __restrict__ b_if,
  const float* __restrict__ W_ic, const float* __restrict__ b_ic,
  const float* __restrict__ W_o,  const float* __restrict__ b_o,
  const float* __restrict__ W_out,const float* __restrict__ b_out,
  float* __restrict__ out)
{
  __shared__ __align__(16) float XR[4*16*VV];     // x ring, 4 blocks   (32 KB)
  __shared__ __align__(16) short XAh[2*2048];     // x A-frags hi       ( 8 KB)
  __shared__ __align__(16) short XAl[2*2048];     // x A-frags lo       ( 8 KB)
  __shared__ __align__(16) float PRE[32*256];     // pre_x ring         (32 KB)
  __shared__ __align__(16) short HAh[2*1024];     // h A-frags hi       ( 4 KB)
  __shared__ __align__(16) short HAl[2*1024];     // h A-frags lo       ( 4 KB)
  __shared__ __align__(16) float HR[32*HH];       // h ring             ( 8 KB)

  const int tid = threadIdx.x;
  const int wv  = tid >> 6;
  const int l   = tid & 63;
  const int row = blockIdx.x;
  const float* xrow = x   + (size_t)row*TT*VV;
  float*       orow = out + (size_t)row*TT*VV;

  if (wv < 4) {
    // ================= CONSUMER: recurrence critical path =================
    const int col = (wv&3)*16 + (l>>2);   // 0..63
    const int q   = l&3;                  // k-quarter of h
    float wh0[16], wh1[16], wh2[16], wh3[16];
    #pragma unroll
    for (int m=0;m<16;++m){
      const size_t kidx = (size_t)(VV + q*16 + m)*HH + col;
      wh0[m]=W_f[kidx]; wh1[m]=W_if[kidx]; wh2[m]=W_ic[kidx]; wh3[m]=W_o[kidx];
    }
    const float b0=b_f[col], b1=b_if[col], b2=b_ic[col], b3=b_o[col];

    if (tid < HH) HR[31*HH + tid] = 0.f;  // h_{-1} = 0
    bar_lds();  // P1 (x blocks 0,1 landed)
    bar_lds();  // P2 (XA 0,1 ready)
    bar_lds();  // P3 (PRE block 0 ready)

    float c = 0.f;
    #pragma unroll 1
    for (int t=0; t<TT; ++t){
      const f32x4* hp = (const f32x4*)&HR[((t+31)&31)*HH + q*16];
      const f32x4 pre4 = *(const f32x4*)&PRE[(t&31)*256 + col*4];
      float d0=0.f,d1=0.f,d2=0.f,d3=0.f;
      #pragma unroll
      for (int m=0;m<4;++m){
        const f32x4 hv = hp[m];
        #pragma unroll
        for (int e=0;e<4;++e){
          const float s = hv[e];
          d0 = fmaf(s, wh0[m*4+e], d0);
          d1 = fmaf(s, wh1[m*4+e], d1);
          d2 = fmaf(s, wh2[m*4+e], d2);
          d3 = fmaf(s, wh3[m*4+e], d3);
        }
      }
      d0 = qsum(d0); d1 = qsum(d1); d2 = qsum(d2); d3 = qsum(d3);
      const float f  = sigm(d0 + pre4[0] + b0);
      const float fi = sigm(d1 + pre4[1] + b1);
      const float ci = tanh_f(d2 + pre4[2] + b2);
      const float o  = sigm(d3 + pre4[3] + b3);
      c = c*f + ci*fi;
      const float hv2 = tanh_f(c) * o;
      if (q==0) HR[(t&31)*HH + col] = hv2;
      bar_lds();
    }
    bar_lds();  // epilogue barrier
  } else {
    // ================= PRODUCER: MFMA pre_x + logits + staging ============
    const int pv = wv - 4;            // 0..3
    const int pt = pv*64 + l;         // 0..255

    // --- B-fragments for pre_x: wave owns n-tiles pv*4..pv*4+3 (n = col*4+g)
    short8 Bh[4][4], Bl[4][4];
    #pragma unroll
    for (int ntl=0; ntl<4; ++ntl){
      const int n = (pv*4+ntl)*16 + (l&15);
      const int g = n&3, colw = n>>2;
      const float* Ws = (g==0)?W_f:((g==1)?W_if:((g==2)?W_ic:W_o));
      #pragma unroll
      for (int kk=0;kk<4;++kk){
        float tmp[8];
        #pragma unroll
        for (int j=0;j<8;++j) tmp[j] = Ws[(size_t)(kk*32+(l>>4)*8+j)*HH + colw];
        splitpack(tmp, Bh[ntl][kk], Bl[ntl][kk]);
      }
    }
    // --- B-fragments for logits: wave owns j-tiles pv*2, pv*2+1
    short8 Lh[2][2], Ll[2][2];
    #pragma unroll
    for (int jt=0; jt<2; ++jt){
      const int j = (pv*2+jt)*16 + (l&15);
      #pragma unroll
      for (int kk=0;kk<2;++kk){
        float tmp[8];
        #pragma unroll
        for (int jj=0;jj<8;++jj) tmp[jj] = W_out[(size_t)(kk*32+(l>>4)*8+jj)*VV + j];
        splitpack(tmp, Lh[jt][kk], Ll[jt][kk]);
      }
    }

    // ---- helpers as lambdas
    auto GLOAD = [&](int b){
      #pragma unroll
      for (int i=0;i<2;++i){
        const float* src = xrow + (size_t)b*16*VV + pv*512 + i*256 + l*4;
        float* dst = &XR[(b&3)*2048 + pv*512 + i*256];
        gload16(src, dst);
      }
    };
    auto CONV = [&](int b){
      if (pt < 256){
        const int buf=b&1, kk=pt>>6, qq=(pt>>4)&3, s=pt&15;
        const float* src = &XR[(b&3)*2048 + s*VV + kk*32 + qq*8];
        float tmp[8];
        #pragma unroll
        for (int j=0;j<8;++j) tmp[j] = src[j];
        short8 hi, lo; splitpack(tmp, hi, lo);
        *(short8*)&XAh[XA_IDX(buf,kk,qq,s)] = hi;
        *(short8*)&XAl[XA_IDX(buf,kk,qq,s)] = lo;
      }
    };
    auto PREB = [&](int b){
      const int buf = b&1;
      short8 Ah[4], Al[4];
      #pragma unroll
      for (int kk=0;kk<4;++kk){
        Ah[kk] = *(const short8*)&XAh[XA_IDX(buf,kk,(l>>4),(l&15))];
        Al[kk] = *(const short8*)&XAl[XA_IDX(buf,kk,(l>>4),(l&15))];
      }
      #pragma unroll
      for (int ntl=0; ntl<4; ++ntl){
        f32x4 acc = {0.f,0.f,0.f,0.f};
        #pragma unroll
        for (int kk=0;kk<4;++kk){
          acc = __builtin_amdgcn_mfma_f32_16x16x32_bf16(Al[kk], Bh[ntl][kk], acc, 0,0,0);
          acc = __builtin_amdgcn_mfma_f32_16x16x32_bf16(Ah[kk], Bl[ntl][kk], acc, 0,0,0);
          acc = __builtin_amdgcn_mfma_f32_16x16x32_bf16(Ah[kk], Bh[ntl][kk], acc, 0,0,0);
        }
        const int n  = (pv*4+ntl)*16 + (l&15);
        const int s0 = buf*16 + (l>>4)*4;
        #pragma unroll
        for (int r=0;r<4;++r) PRE[(s0+r)*256 + n] = acc[r];
      }
    };
    auto LOGB = [&](int b){
      const int buf = b&1;
      short8 Ah[2], Al[2];
      #pragma unroll
      for (int kk=0;kk<2;++kk){
        Ah[kk] = *(const short8*)&HAh[HA_IDX(buf,kk,(l>>4),(l&15))];
        Al[kk] = *(const short8*)&HAl[HA_IDX(buf,kk,(l>>4),(l&15))];
      }
      #pragma unroll
      for (int jt=0; jt<2; ++jt){
        f32x4 acc = {0.f,0.f,0.f,0.f};
        #pragma unroll
        for (int kk=0;kk<2;++kk){
          acc = __builtin_amdgcn_mfma_f32_16x16x32_bf16(Al[kk], Lh[jt][kk], acc, 0,0,0);
          acc = __builtin_amdgcn_mfma_f32_16x16x32_bf16(Ah[kk], Ll[jt][kk], acc, 0,0,0);
          acc = __builtin_amdgcn_mfma_f32_16x16x32_bf16(Ah[kk], Lh[jt][kk], acc, 0,0,0);
        }
        const int j  = (pv*2+jt)*16 + (l&15);
        const int t0 = b*16 + (l>>4)*4;
        #pragma unroll
        for (int r=0;r<4;++r) orow[(size_t)(t0+r)*VV + j] = acc[r];
      }
    };
    auto RELAY = [&](int hs){   // relayout h_hs into HA (threads pt<8)
      if (pt < 8){
        const int kk = pt>>2, qq = pt&3;
        const int buf = (hs>>4)&1, s = hs&15;
        const float* src = &HR[(hs&31)*HH + kk*32 + qq*8];
        float tmp[8];
        #pragma unroll
        for (int j=0;j<8;++j) tmp[j] = src[j];
        short8 hi, lo; splitpack(tmp, hi, lo);
        *(short8*)&HAh[HA_IDX(buf,kk,qq,s)] = hi;
        *(short8*)&HAl[HA_IDX(buf,kk,qq,s)] = lo;
      }
    };

    // ---- prologue: stage x blocks 0..2, convert 0,1, pre_x block 0
    GLOAD(0); GLOAD(1); GLOAD(2);
    asm volatile("s_waitcnt vmcnt(2)" ::: "memory");  // blocks 0,1 landed (own wave)
    bar_lds();  // P1: cross-wave landing
    CONV(0); CONV(1);
    bar_lds();  // P2
    PREB(0);
    bar_lds();  // P3

    #pragma unroll 1
    for (int t=0; t<TT; ++t){
      if (t >= 1) RELAY(t-1);
      const int slot = t&15, blk = t>>4;
      if (slot==0){ if (blk+1 < NB) PREB(blk+1); }
      else if (slot==1){ if (blk >= 1) LOGB(blk-1); }
      else if (slot==2){ if (blk+3 < NB) GLOAD(blk+3); }
      else if (slot==3){ if (blk+2 < NB) asm volatile("s_waitcnt vmcnt(2)" ::: "memory"); }
      else if (slot==4){ if (blk+2 < NB) CONV(blk+2); }
      bar_lds();
    }
    RELAY(TT-1);
    bar_lds();  // epilogue barrier (matches consumer)
    LOGB(NB-1);
  }
}

// epilogue: out = softmax(out + b_out) over rows of 128; one wave per row
__global__ __launch_bounds__(256) void softmax_k(float* __restrict__ out,
                                                 const float* __restrict__ b_out)
{
  const int r = blockIdx.x*4 + (threadIdx.x>>6);
  const int l = threadIdx.x & 63;
  float2* p = (float2*)(out + (size_t)r*VV);
  const float2* bb = (const float2*)b_out;
  float2 v = p[l];
  const float2 b2 = bb[l];
  v.x += b2.x; v.y += b2.y;
  float m = fmaxf(v.x, v.y);
  #pragma unroll
  for (int d=1; d<64; d<<=1) m = fmaxf(m, __shfl_xor(m, d));
  float e0 = __expf(v.x - m), e1 = __expf(v.y - m);
  float s = e0 + e1;
  #pragma unroll
  for (int d=1; d<64; d<<=1) s += __shfl_xor(s, d);
  const float rs = frcp(s);
  p[l] = make_float2(e0*rs, e1*rs);
}

extern "C" void kernel_launch(void* const* d_in, const int* in_sizes, int n_in,
                              void* d_out, int out_size, void* d_ws, size_t ws_size,
                              hipStream_t stream) {
  const float* x     = (const float*)d_in[0];
  const float* W_f   = (const float*)d_in[1];
  const float* b_f   = (const float*)d_in[2];
  const float* W_if  = (const float*)d_in[3];
  const float* b_if  = (const float*)d_in[4];
  const float* W_ic  = (const float*)d_in[5];
  const float* b_ic  = (const float*)d_in[6];
  const float* W_o   = (const float*)d_in[7];
  const float* b_o   = (const float*)d_in[8];
  const float* W_out = (const float*)d_in[9];
  const float* b_out = (const float*)d_in[10];
  float* out = (float*)d_out;

  hipLaunchKernelGGL(lstm_k, dim3(256), dim3(512), 0, stream,
                     x, W_f, b_f, W_if, b_if, W_ic, b_ic, W_o, b_o,
                     W_out, b_out, out);
  hipLaunchKernelGGL(softmax_k, dim3(256*TT/4), dim3(256), 0, stream, out, b_out);
}